// Round 1
// baseline (665.743 us; speedup 1.0000x reference)
//
#include <hip/hip_runtime.h>
#include <hip/hip_bf16.h>

#define BB 16384
#define TT 10
#define HH 256
#define NG 1024
#define NLAB 500

typedef __attribute__((ext_vector_type(8))) __bf16 bf16x8;
typedef __attribute__((ext_vector_type(4))) float f32x4;
typedef __attribute__((ext_vector_type(8))) short short8v;

__device__ __forceinline__ unsigned short f2bf(float f) {
  union { float f; unsigned int u; } x; x.f = f;
  unsigned int r = 0x7fffu + ((x.u >> 16) & 1u);
  return (unsigned short)((x.u + r) >> 16);
}

__device__ __forceinline__ float sigm(float x) {
  return __builtin_amdgcn_rcpf(1.f + exp2f(-1.4426950408889634f * x));
}
__device__ __forceinline__ float tanh_(float x) {
  float ax = fabsf(x);
  float e = exp2f(-2.8853900817779268f * ax);          // exp(-2|x|)
  float r = (1.f - e) * __builtin_amdgcn_rcpf(1.f + e);
  return copysignf(r, x);
}

// async global->LDS, 16B per lane, LDS dest = wave-uniform base + lane*16
__device__ __forceinline__ void gload_lds16(const unsigned short* g, unsigned short* l) {
  __builtin_amdgcn_global_load_lds(
      (const __attribute__((address_space(1))) unsigned int*)g,
      (__attribute__((address_space(3))) unsigned int*)l, 16, 0, 0);
}

// ---------------- weight/bias prep: fragment-linear bf16 layout ----------------
// W frag layout: [kstep][colblk(16 cols)][lane(64)][8 elems]; lane = (n%16) + 16*(k8),
// elem = k%8, i.e. B-operand of mfma_f32_16x16x32_bf16 reads lane*16B linearly.
__global__ void prep_w(const float* __restrict__ Wih0, const float* __restrict__ Whh0,
                       const float* __restrict__ bih0, const float* __restrict__ bhh0,
                       const float* __restrict__ Wih1, const float* __restrict__ Whh1,
                       const float* __restrict__ bih1, const float* __restrict__ bhh1,
                       const float* __restrict__ Wout, const float* __restrict__ bout,
                       unsigned short* __restrict__ w0f, unsigned short* __restrict__ w1f,
                       unsigned short* __restrict__ woutf, float* __restrict__ bias0,
                       float* __restrict__ bias1, float* __restrict__ boutp) {
  int i = blockIdx.x * 256 + threadIdx.x;
  if (i < 327680) {                       // W0cat: K = 64(x pad) + 256(h) = 320 -> 10 ksteps
    int e = i & 7, ln = (i >> 3) & 63, cb = (i >> 9) & 63, ks = i >> 15;
    int n = (cb << 4) + (ln & 15);
    int k = (ks << 5) + ((ln >> 4) << 3) + e;
    float v;
    if (k < 64) v = (k < 39) ? Wih0[n * 39 + k] : 0.f;
    else        v = Whh0[n * 256 + (k - 64)];
    w0f[i] = f2bf(v);
  } else if (i < 851968) {                // W1cat: K = 256(h1) + 256(h2) = 512 -> 16 ksteps
    int j = i - 327680;
    int e = j & 7, ln = (j >> 3) & 63, cb = (j >> 9) & 63, ks = j >> 15;
    int n = (cb << 4) + (ln & 15);
    int k = (ks << 5) + ((ln >> 4) << 3) + e;
    float v = (k < 256) ? Wih1[n * 256 + k] : Whh1[n * 256 + (k - 256)];
    w1f[j] = f2bf(v);
  } else if (i < 983040) {                // Wout: 512(pad) x 256 -> 8 ksteps x 32 colblks
    int j = i - 851968;
    int e = j & 7, ln = (j >> 3) & 63, cb = (j >> 9) & 31, ks = j >> 14;
    int n = (cb << 4) + (ln & 15);
    int k = (ks << 5) + ((ln >> 4) << 3) + e;
    float v = (n < NLAB) ? Wout[n * 256 + k] : 0.f;
    woutf[j] = f2bf(v);
  } else {
    int j = i - 983040;
    if (j < 1024)       bias0[j] = bih0[j] + bhh0[j];
    else if (j < 2048)  bias1[j - 1024] = bih1[j - 1024] + bhh1[j - 1024];
    else if (j < 2560) { int n = j - 2048; boutp[n] = (n < NLAB) ? bout[n] : 0.f; }
  }
}

// ---------------- embedding gather -> x in A-frag-linear layout ----------------
// xfrag: [tile(256)][t(10)][kc(2)][rb(4)][lane(64)][8] bf16; element (b,t,k):
// tile=b/64, rb=(b/16)%4, lane=(b%16)+16*((k%32)/8), elem=k%8, kc=k/32. k in [39,64) zero.
__global__ void gather_x(const int* __restrict__ car_idx, const int* __restrict__ region_idx,
                         const int* __restrict__ poi_idx, const int* __restrict__ week_idx,
                         const int* __restrict__ time_idx,
                         const float* __restrict__ car_emb, const float* __restrict__ region_emb,
                         const float* __restrict__ poi_emb, const float* __restrict__ week_emb,
                         const float* __restrict__ time_emb,
                         unsigned short* __restrict__ xfrag) {
  int tid = blockIdx.x * 256 + threadIdx.x;
  if (tid >= BB * TT) return;
  int t = tid / BB;
  int b = tid - t * BB;
  int ii = b * TT + t;
  float v[64];
#pragma unroll
  for (int k = 0; k < 64; ++k) v[k] = 0.f;
  { const float* p = car_emb + (size_t)car_idx[ii] * 16;
#pragma unroll
    for (int k = 0; k < 16; ++k) v[k] = p[k]; }
  { const float* p = region_emb + (size_t)region_idx[ii] * 8;
#pragma unroll
    for (int k = 0; k < 8; ++k) v[16 + k] = p[k]; }
  { const float* p = poi_emb + (size_t)poi_idx[ii] * 4;
#pragma unroll
    for (int k = 0; k < 4; ++k) v[24 + k] = p[k]; }
  { const float* p = week_emb + (size_t)week_idx[ii] * 3;
#pragma unroll
    for (int k = 0; k < 3; ++k) v[28 + k] = p[k]; }
  { const float* p = time_emb + (size_t)time_idx[ii] * 8;
#pragma unroll
    for (int k = 0; k < 8; ++k) v[31 + k] = p[k]; }

  int tile = b >> 6, rb = (b >> 4) & 3, lrow = b & 15;
  size_t base = ((size_t)tile * TT + t) * 4096;
#pragma unroll
  for (int c = 0; c < 8; ++c) {          // octet of k: k = 8c..8c+7
    int kc = c >> 2;
    int lane = lrow + ((c & 3) << 4);
    size_t off = base + (size_t)((((kc << 2) + rb) << 6) + lane) * 8;
    short8v s;
#pragma unroll
    for (int e = 0; e < 8; ++e) s[e] = (short)f2bf(v[c * 8 + e]);
    *(short8v*)(xfrag + off) = s;
  }
}

// ---------------- fused 2-layer LSTM + output projection ----------------
// 256 blocks x 512 threads; block owns 64 batch rows, runs all T steps + proj.
// Wave w owns gate cols {gc*256 + 32w .. +32} for gc in {i,f,g,o}; c-state in VGPRs.
__device__ __forceinline__ void gemm_gates(f32x4 (&acc)[4][2][4],
    const unsigned short* __restrict__ wsrc, int nks, int split,
    const unsigned short* bufA, const unsigned short* bufB,
    unsigned short* wbuf, int lane, int wid) {
  for (int ks = 0; ks < nks; ++ks) {
    const unsigned short* src = wsrc + (size_t)ks * 32768;
#pragma unroll
    for (int r = 0; r < 8; ++r) {        // stage 64KB W chunk, 8 x 1KB per wave
      int seg = r * 8 + wid;
      gload_lds16(src + seg * 512 + lane * 8, wbuf + seg * 512);
    }
    __syncthreads();                     // vmcnt(0)+barrier: chunk ready
    const unsigned short* ab = (ks < split) ? bufA : bufB;
    int kc = (ks < split) ? ks : ks - split;
    bf16x8 a[4];
#pragma unroll
    for (int rb = 0; rb < 4; ++rb)
      a[rb] = *(const bf16x8*)(ab + (size_t)((((kc << 2) + rb) << 6) + lane) * 8);
#pragma unroll
    for (int gc = 0; gc < 4; ++gc)
#pragma unroll
      for (int nb = 0; nb < 2; ++nb) {
        bf16x8 bb = *(const bf16x8*)(wbuf + (size_t)((((gc << 4) + (wid << 1) + nb) << 6) + lane) * 8);
#pragma unroll
        for (int rb = 0; rb < 4; ++rb)
          acc[gc][nb][rb] = __builtin_amdgcn_mfma_f32_16x16x32_bf16(a[rb], bb, acc[gc][nb][rb], 0, 0, 0);
      }
    __syncthreads();                     // all reads of wbuf done before next overwrite
  }
}

__device__ __forceinline__ void cell_update(f32x4 (&acc)[4][2][4], f32x4 (&cst)[2][4],
    unsigned short* hbuf, int lane, int wid) {
  int lrow = ((lane >> 4) << 2);
  int l15 = lane & 15;
#pragma unroll
  for (int nb = 0; nb < 2; ++nb) {
    int jw = (nb << 4) + l15;            // cell index within wave's 32 cols
    int lane_dst_base = ((jw >> 3) << 4);
    int elem = jw & 7;
#pragma unroll
    for (int rb = 0; rb < 4; ++rb) {
#pragma unroll
      for (int reg = 0; reg < 4; ++reg) {
        float iv = sigm(acc[0][nb][rb][reg]);
        float fv = sigm(acc[1][nb][rb][reg]);
        float gv = tanh_(acc[2][nb][rb][reg]);
        float ov = sigm(acc[3][nb][rb][reg]);
        float c = fv * cst[nb][rb][reg] + iv * gv;
        cst[nb][rb][reg] = c;
        float h = ov * tanh_(c);
        // write h into A-frag layout: kc = wid, row r = rb*16 + lrow + reg
        int lane_dst = lrow + reg + lane_dst_base;
        hbuf[(size_t)((((wid << 2) + rb) << 6) + lane_dst) * 8 + elem] = f2bf(h);
      }
    }
  }
}

__global__ __launch_bounds__(512) void lstm_fused(
    const unsigned short* __restrict__ xfrag, const unsigned short* __restrict__ w0f,
    const unsigned short* __restrict__ w1f, const unsigned short* __restrict__ woutf,
    const float* __restrict__ bias0, const float* __restrict__ bias1,
    const float* __restrict__ boutp, float* __restrict__ out) {
  __shared__ __align__(16) unsigned short h1s[16384];   // [kc8][rb4][lane64][8] bf16
  __shared__ __align__(16) unsigned short h2s[16384];
  __shared__ __align__(16) unsigned short xts[4096];    // [kc2][rb4][lane64][8]
  __shared__ __align__(16) unsigned short wbuf[32768];  // [colblk64][lane64][8]

  int tid = threadIdx.x;
  int lane = tid & 63;
  int wid = tid >> 6;
  int tile = blockIdx.x;
  int b0 = tile << 6;
  int l15 = lane & 15;

  {
    short8v z = {0, 0, 0, 0, 0, 0, 0, 0};
    short8v* p1 = (short8v*)h1s;
    short8v* p2 = (short8v*)h2s;
    for (int i = tid; i < 2048; i += 512) { p1[i] = z; p2[i] = z; }
  }

  f32x4 c1[2][4], c2[2][4];
#pragma unroll
  for (int nb = 0; nb < 2; ++nb)
#pragma unroll
    for (int rb = 0; rb < 4; ++rb) {
      c1[nb][rb] = (f32x4){0.f, 0.f, 0.f, 0.f};
      c2[nb][rb] = (f32x4){0.f, 0.f, 0.f, 0.f};
    }

  f32x4 acc[4][2][4];

  for (int t = 0; t < TT; ++t) {
    // stage x_t tile (8KB, 1 round)
    gload_lds16(xfrag + ((size_t)(tile * TT + t)) * 4096 + wid * 512 + lane * 8,
                xts + wid * 512);
    __syncthreads();

    // ---- layer 0: gates = [x_t | h1] @ W0cat^T + bias0
#pragma unroll
    for (int gc = 0; gc < 4; ++gc)
#pragma unroll
      for (int nb = 0; nb < 2; ++nb) {
        float bv = bias0[(gc << 8) + (wid << 5) + (nb << 4) + l15];
#pragma unroll
        for (int rb = 0; rb < 4; ++rb) acc[gc][nb][rb] = (f32x4){bv, bv, bv, bv};
      }
    gemm_gates(acc, w0f, 10, 2, xts, h1s, wbuf, lane, wid);
    cell_update(acc, c1, h1s, lane, wid);
    __syncthreads();

    // ---- layer 1: gates = [h1_t | h2] @ W1cat^T + bias1
#pragma unroll
    for (int gc = 0; gc < 4; ++gc)
#pragma unroll
      for (int nb = 0; nb < 2; ++nb) {
        float bv = bias1[(gc << 8) + (wid << 5) + (nb << 4) + l15];
#pragma unroll
        for (int rb = 0; rb < 4; ++rb) acc[gc][nb][rb] = (f32x4){bv, bv, bv, bv};
      }
    gemm_gates(acc, w1f, 16, 8, h1s, h2s, wbuf, lane, wid);
    cell_update(acc, c2, h2s, lane, wid);
    __syncthreads();
  }

  // ---- output projection: out = h2 @ Wout^T + bout; wave w owns cols [64w, 64w+64)
  f32x4 acco[4][4];
#pragma unroll
  for (int nb = 0; nb < 4; ++nb) {
    float bv = boutp[(wid << 6) + (nb << 4) + l15];
#pragma unroll
    for (int rb = 0; rb < 4; ++rb) acco[nb][rb] = (f32x4){bv, bv, bv, bv};
  }
  for (int ks = 0; ks < 8; ++ks) {
    bf16x8 a[4];
#pragma unroll
    for (int rb = 0; rb < 4; ++rb)
      a[rb] = *(const bf16x8*)(h2s + (size_t)((((ks << 2) + rb) << 6) + lane) * 8);
#pragma unroll
    for (int nb = 0; nb < 4; ++nb) {
      bf16x8 bb = *(const bf16x8*)(woutf + (size_t)((((ks << 5) + (wid << 2) + nb) << 6) + lane) * 8);
#pragma unroll
      for (int rb = 0; rb < 4; ++rb)
        acco[nb][rb] = __builtin_amdgcn_mfma_f32_16x16x32_bf16(a[rb], bb, acco[nb][rb], 0, 0, 0);
    }
  }
#pragma unroll
  for (int nb = 0; nb < 4; ++nb) {
    int n = (wid << 6) + (nb << 4) + l15;
    if (n < NLAB) {
#pragma unroll
      for (int rb = 0; rb < 4; ++rb)
#pragma unroll
        for (int reg = 0; reg < 4; ++reg) {
          int r = (rb << 4) + ((lane >> 4) << 2) + reg;
          out[(size_t)(b0 + r) * NLAB + n] = acco[nb][rb][reg];
        }
    }
  }
}

extern "C" void kernel_launch(void* const* d_in, const int* in_sizes, int n_in,
                              void* d_out, int out_size, void* d_ws, size_t ws_size,
                              hipStream_t stream) {
  const int* car_idx    = (const int*)d_in[0];
  const int* region_idx = (const int*)d_in[1];
  const int* poi_idx    = (const int*)d_in[2];
  const int* week_idx   = (const int*)d_in[3];
  const int* time_idx   = (const int*)d_in[4];
  const float* car_emb    = (const float*)d_in[5];
  const float* region_emb = (const float*)d_in[6];
  const float* poi_emb    = (const float*)d_in[7];
  const float* week_emb   = (const float*)d_in[8];
  const float* time_emb   = (const float*)d_in[9];
  const float* Wih0 = (const float*)d_in[10];
  const float* Whh0 = (const float*)d_in[11];
  const float* bih0 = (const float*)d_in[12];
  const float* bhh0 = (const float*)d_in[13];
  const float* Wih1 = (const float*)d_in[14];
  const float* Whh1 = (const float*)d_in[15];
  const float* bih1 = (const float*)d_in[16];
  const float* bhh1 = (const float*)d_in[17];
  const float* Wout = (const float*)d_in[18];
  const float* bout = (const float*)d_in[19];

  // workspace layout (16B aligned sections), ~22.9 MB total
  unsigned short* xfrag = (unsigned short*)d_ws;      // 10,485,760 bf16
  unsigned short* w0f   = xfrag + 10485760;           // 327,680
  unsigned short* w1f   = w0f + 327680;               // 524,288
  unsigned short* woutf = w1f + 524288;               // 131,072
  float* bias0 = (float*)(woutf + 131072);            // 1024
  float* bias1 = bias0 + 1024;                        // 1024
  float* boutp = bias1 + 1024;                        // 512

  prep_w<<<3850, 256, 0, stream>>>(Wih0, Whh0, bih0, bhh0, Wih1, Whh1, bih1, bhh1,
                                   Wout, bout, w0f, w1f, woutf, bias0, bias1, boutp);
  gather_x<<<640, 256, 0, stream>>>(car_idx, region_idx, poi_idx, week_idx, time_idx,
                                    car_emb, region_emb, poi_emb, week_emb, time_emb, xfrag);
  lstm_fused<<<256, 512, 0, stream>>>(xfrag, w0f, w1f, woutf, bias0, bias1, boutp,
                                      (float*)d_out);
}

// Round 3
// 501.967 us; speedup vs baseline: 1.3263x; 1.3263x over previous
//
#include <hip/hip_runtime.h>
#include <hip/hip_bf16.h>

#define BB 16384
#define TT 10
#define HH 256
#define NLAB 500

typedef __attribute__((ext_vector_type(8))) __bf16 bf16x8;
typedef __attribute__((ext_vector_type(4))) float f32x4;
typedef __attribute__((ext_vector_type(8))) short short8v;

__device__ __forceinline__ unsigned short f2bf(float f) {
  union { float f; unsigned int u; } x; x.f = f;
  unsigned int r = 0x7fffu + ((x.u >> 16) & 1u);
  return (unsigned short)((x.u + r) >> 16);
}

__device__ __forceinline__ float sigm(float x) {
  return __builtin_amdgcn_rcpf(1.f + exp2f(-1.4426950408889634f * x));
}
__device__ __forceinline__ float tanh_(float x) {
  float ax = fabsf(x);
  float e = exp2f(-2.8853900817779268f * ax);          // exp(-2|x|)
  float r = (1.f - e) * __builtin_amdgcn_rcpf(1.f + e);
  return copysignf(r, x);
}

// async global->LDS, 16B per lane; global src is PER-LANE, LDS dest = uniform base + lane*16
__device__ __forceinline__ void gload_lds16(const unsigned short* g, unsigned short* l) {
  __builtin_amdgcn_global_load_lds(
      (const __attribute__((address_space(1))) unsigned int*)g,
      (__attribute__((address_space(3))) unsigned int*)l, 16, 0, 0);
}

#define SCHED0() __builtin_amdgcn_sched_barrier(0)

// ---------------- weight/bias prep: fragment-linear bf16 layout ----------------
// Chunk stream (each chunk 16384 bf16 = 32 KB = 32 colblks x 64 lanes x 8):
//   chunks 0..19  : W0cat (K=320 -> 10 ksteps x 2 gate-halves)
//   chunks 20..51 : W1cat (K=512 -> 16 ksteps x 2 gate-halves)
//   chunks 52..59 : Wout  (K=256 -> 8 ksteps, 32 colblks = 512 padded out cols)
__global__ void prep_w(const float* __restrict__ Wih0, const float* __restrict__ Whh0,
                       const float* __restrict__ bih0, const float* __restrict__ bhh0,
                       const float* __restrict__ Wih1, const float* __restrict__ Whh1,
                       const float* __restrict__ bih1, const float* __restrict__ bhh1,
                       const float* __restrict__ Wout, const float* __restrict__ bout,
                       unsigned short* __restrict__ wall, float* __restrict__ bblob) {
  int i = blockIdx.x * 256 + threadIdx.x;
  if (i < 327680) {                       // W0cat
    int e = i & 7, ln = (i >> 3) & 63, cb = (i >> 9) & 63, ks = i >> 15;
    int n = (cb << 4) + (ln & 15);
    int k = (ks << 5) + ((ln >> 4) << 3) + e;
    float v;
    if (k < 64) v = (k < 39) ? Wih0[n * 39 + k] : 0.f;
    else        v = Whh0[n * 256 + (k - 64)];
    wall[i] = f2bf(v);
  } else if (i < 851968) {                // W1cat
    int j = i - 327680;
    int e = j & 7, ln = (j >> 3) & 63, cb = (j >> 9) & 63, ks = j >> 15;
    int n = (cb << 4) + (ln & 15);
    int k = (ks << 5) + ((ln >> 4) << 3) + e;
    float v = (k < 256) ? Wih1[n * 256 + k] : Whh1[n * 256 + (k - 256)];
    wall[i] = f2bf(v);
  } else if (i < 983040) {                // Wout
    int j = i - 851968;
    int e = j & 7, ln = (j >> 3) & 63, cb = (j >> 9) & 31, ks = j >> 14;
    int n = (cb << 4) + (ln & 15);
    int k = (ks << 5) + ((ln >> 4) << 3) + e;
    float v = (n < NLAB) ? Wout[n * 256 + k] : 0.f;
    wall[i] = f2bf(v);
  } else {                                // bias blob: 4096 f32 (16 KB, padded)
    int j = i - 983040;
    float v = 0.f;
    if (j < 1024)       v = bih0[j] + bhh0[j];
    else if (j < 2048)  v = bih1[j - 1024] + bhh1[j - 1024];
    else if (j < 2560) { int n = j - 2048; v = (n < NLAB) ? bout[n] : 0.f; }
    bblob[j] = v;
  }
}

// ---------------- embedding gather -> x in A-frag-linear layout ----------------
__global__ void gather_x(const int* __restrict__ car_idx, const int* __restrict__ region_idx,
                         const int* __restrict__ poi_idx, const int* __restrict__ week_idx,
                         const int* __restrict__ time_idx,
                         const float* __restrict__ car_emb, const float* __restrict__ region_emb,
                         const float* __restrict__ poi_emb, const float* __restrict__ week_emb,
                         const float* __restrict__ time_emb,
                         unsigned short* __restrict__ xfrag) {
  int tid = blockIdx.x * 256 + threadIdx.x;
  if (tid >= BB * TT) return;
  int t = tid / BB;
  int b = tid - t * BB;
  int ii = b * TT + t;
  float v[64];
#pragma unroll
  for (int k = 0; k < 64; ++k) v[k] = 0.f;
  { const float* p = car_emb + (size_t)car_idx[ii] * 16;
#pragma unroll
    for (int k = 0; k < 16; ++k) v[k] = p[k]; }
  { const float* p = region_emb + (size_t)region_idx[ii] * 8;
#pragma unroll
    for (int k = 0; k < 8; ++k) v[16 + k] = p[k]; }
  { const float* p = poi_emb + (size_t)poi_idx[ii] * 4;
#pragma unroll
    for (int k = 0; k < 4; ++k) v[24 + k] = p[k]; }
  { const float* p = week_emb + (size_t)week_idx[ii] * 3;
#pragma unroll
    for (int k = 0; k < 3; ++k) v[28 + k] = p[k]; }
  { const float* p = time_emb + (size_t)time_idx[ii] * 8;
#pragma unroll
    for (int k = 0; k < 8; ++k) v[31 + k] = p[k]; }

  int tile = b >> 6, rb = (b >> 4) & 3, lrow = b & 15;
  size_t base = ((size_t)tile * TT + t) * 4096;
#pragma unroll
  for (int c = 0; c < 8; ++c) {
    int kc = c >> 2;
    int lane = lrow + ((c & 3) << 4);
    size_t off = base + (size_t)((((kc << 2) + rb) << 6) + lane) * 8;
    short8v s;
#pragma unroll
    for (int e = 0; e < 8; ++e) s[e] = (short)f2bf(v[c * 8 + e]);
    *(short8v*)(xfrag + off) = s;
  }
}

// ---------------- fused LSTM: pipelined chunk consumer ----------------
// Per chunk: {issue next chunk's 4 global_load_lds; vmcnt(4) [counted: next stays
// in flight]; s_barrier; ds_read frags; 16 MFMA; lgkmcnt(0); s_barrier}.
template <int HALF>
__device__ __forceinline__ void chunk_step(
    f32x4 (&acc)[4][2][4], bf16x8 (&a)[4], const unsigned short* abuf,
    const unsigned short* wcur, const unsigned short* nsrc, unsigned short* ndst,
    const unsigned short* xsrc, unsigned short* xdst, int dox,
    int lane, int wid) {
  if (dox) gload_lds16(xsrc + wid * 512 + lane * 8, xdst + wid * 512);
#pragma unroll
  for (int r = 0; r < 4; ++r) {
    int seg = r * 8 + wid;
    gload_lds16(nsrc + seg * 512 + lane * 8, ndst + seg * 512);
  }
  if (dox) { asm volatile("s_waitcnt vmcnt(5)" ::: "memory"); }
  else     { asm volatile("s_waitcnt vmcnt(4)" ::: "memory"); }
  SCHED0();
  __builtin_amdgcn_s_barrier();
  SCHED0();
  if (HALF == 0) {
#pragma unroll
    for (int rb = 0; rb < 4; ++rb)
      a[rb] = *(const bf16x8*)(abuf + (size_t)((rb << 6) + lane) * 8);
  }
#pragma unroll
  for (int gcl = 0; gcl < 2; ++gcl)
#pragma unroll
    for (int nb = 0; nb < 2; ++nb) {
      bf16x8 bb = *(const bf16x8*)(wcur + (size_t)((((gcl << 4) + (wid << 1) + nb) << 6) + lane) * 8);
#pragma unroll
      for (int rb = 0; rb < 4; ++rb)
        acc[HALF * 2 + gcl][nb][rb] =
            __builtin_amdgcn_mfma_f32_16x16x32_bf16(a[rb], bb, acc[HALF * 2 + gcl][nb][rb], 0, 0, 0);
    }
  asm volatile("s_waitcnt lgkmcnt(0)" ::: "memory");
  SCHED0();
  __builtin_amdgcn_s_barrier();
  SCHED0();
}

__device__ __forceinline__ void cell_update(f32x4 (&acc)[4][2][4], f32x4 (&cst)[2][4],
    unsigned short* hbuf, int lane, int wid) {
  int lrow = ((lane >> 4) << 2);
  int l15 = lane & 15;
#pragma unroll
  for (int nb = 0; nb < 2; ++nb) {
    int jw = (nb << 4) + l15;
    int lane_dst_base = ((jw >> 3) << 4);
    int elem = jw & 7;
#pragma unroll
    for (int rb = 0; rb < 4; ++rb) {
#pragma unroll
      for (int reg = 0; reg < 4; ++reg) {
        float iv = sigm(acc[0][nb][rb][reg]);
        float fv = sigm(acc[1][nb][rb][reg]);
        float gv = tanh_(acc[2][nb][rb][reg]);
        float ov = sigm(acc[3][nb][rb][reg]);
        float c = fv * cst[nb][rb][reg] + iv * gv;
        cst[nb][rb][reg] = c;
        float h = ov * tanh_(c);
        int lane_dst = lrow + reg + lane_dst_base;
        hbuf[(size_t)((((wid << 2) + rb) << 6) + lane_dst) * 8 + elem] = f2bf(h);
      }
    }
  }
  asm volatile("s_waitcnt lgkmcnt(0)" ::: "memory");
  SCHED0();
}

__global__ __launch_bounds__(512) void lstm_fused(
    const unsigned short* __restrict__ xfrag, const unsigned short* __restrict__ wall,
    const float* __restrict__ bblob, float* __restrict__ out) {
  __shared__ __align__(16) unsigned short h1s[16384];    // 32 KB
  __shared__ __align__(16) unsigned short h2s[16384];    // 32 KB
  __shared__ __align__(16) unsigned short xts[4096];     // 8 KB
  __shared__ __align__(16) unsigned short wbls[2][16384];// 2 x 32 KB
  __shared__ __align__(16) float bls[4096];              // 16 KB

  int tid = threadIdx.x;
  int lane = tid & 63;
  int wid = tid >> 6;
  int tile = blockIdx.x;
  int b0 = tile << 6;
  int l15 = lane & 15;

  // zero h states
  {
    short8v z = {0, 0, 0, 0, 0, 0, 0, 0};
    short8v* p1 = (short8v*)h1s;
    short8v* p2 = (short8v*)h2s;
    for (int i = tid; i < 2048; i += 512) { p1[i] = z; p2[i] = z; }
  }
  // prologue staging: bias (2 wave-loads), x_0 (1), chunk0 (4)
#pragma unroll
  for (int r = 0; r < 2; ++r) {
    int seg = r * 8 + wid;
    gload_lds16((const unsigned short*)bblob + seg * 512 + lane * 8,
                (unsigned short*)bls + seg * 512);           // FIX: per-lane src offset
  }
  gload_lds16(xfrag + (size_t)(tile * TT) * 4096 + wid * 512 + lane * 8, xts + wid * 512);
#pragma unroll
  for (int r = 0; r < 4; ++r) {
    int seg = r * 8 + wid;
    gload_lds16(wall + seg * 512 + lane * 8, wbls[0] + seg * 512);
  }
  asm volatile("s_waitcnt lgkmcnt(0)" ::: "memory");   // h zeros done
  asm volatile("s_waitcnt vmcnt(4)" ::: "memory");     // bias + x0 done (chunk0 in flight)
  SCHED0();
  __builtin_amdgcn_s_barrier();
  SCHED0();

  f32x4 c1[2][4], c2[2][4];
#pragma unroll
  for (int nb = 0; nb < 2; ++nb)
#pragma unroll
    for (int rb = 0; rb < 4; ++rb) {
      c1[nb][rb] = (f32x4){0.f, 0.f, 0.f, 0.f};
      c2[nb][rb] = (f32x4){0.f, 0.f, 0.f, 0.f};
    }

  f32x4 acc[4][2][4];
  bf16x8 afr[4];

#pragma unroll 1
  for (int t = 0; t < TT; ++t) {
    // ---- layer 0: gates = [x_t | h1] @ W0cat^T + bias0
#pragma unroll
    for (int gc = 0; gc < 4; ++gc)
#pragma unroll
      for (int nb = 0; nb < 2; ++nb) {
        float bv = bls[(gc << 8) + (wid << 5) + (nb << 4) + l15];
#pragma unroll
        for (int rb = 0; rb < 4; ++rb) acc[gc][nb][rb] = (f32x4){bv, bv, bv, bv};
      }
#pragma unroll 1
    for (int ks = 0; ks < 10; ++ks) {
      int j = ks << 1;
      const unsigned short* ab = (ks < 2) ? (xts + (ks << 11)) : (h1s + ((ks - 2) << 11));
      chunk_step<0>(acc, afr, ab, wbls[0], wall + (size_t)(j + 1) * 16384, wbls[1],
                    nullptr, nullptr, 0, lane, wid);
      chunk_step<1>(acc, afr, nullptr, wbls[1], wall + (size_t)(j + 2) * 16384, wbls[0],
                    nullptr, nullptr, 0, lane, wid);
    }
    cell_update(acc, c1, h1s, lane, wid);

    // ---- layer 1: gates = [h1_t | h2] @ W1cat^T + bias1
#pragma unroll
    for (int gc = 0; gc < 4; ++gc)
#pragma unroll
      for (int nb = 0; nb < 2; ++nb) {
        float bv = bls[1024 + (gc << 8) + (wid << 5) + (nb << 4) + l15];
#pragma unroll
        for (int rb = 0; rb < 4; ++rb) acc[gc][nb][rb] = (f32x4){bv, bv, bv, bv};
      }
#pragma unroll 1
    for (int ks = 0; ks < 16; ++ks) {
      int j = 20 + (ks << 1);
      const unsigned short* ab = (ks < 8) ? (h1s + (ks << 11)) : (h2s + ((ks - 8) << 11));
      int dox = (ks == 15 && t < TT - 1) ? 1 : 0;
      const unsigned short* xsrc = dox ? (xfrag + (size_t)(tile * TT + t + 1) * 4096) : nullptr;
      const unsigned short* nx2 =
          (j + 2 <= 51) ? (wall + (size_t)(j + 2) * 16384)
                        : ((t < TT - 1) ? wall : (wall + (size_t)52 * 16384));
      chunk_step<0>(acc, afr, ab, wbls[0], wall + (size_t)(j + 1) * 16384, wbls[1],
                    xsrc, xts, dox, lane, wid);
      chunk_step<1>(acc, afr, nullptr, wbls[1], nx2, wbls[0],
                    nullptr, nullptr, 0, lane, wid);
    }
    cell_update(acc, c2, h2s, lane, wid);
  }

  // ---- output projection: out = h2 @ Wout^T + bout
  f32x4 acco[4][4];
#pragma unroll
  for (int nb = 0; nb < 4; ++nb) {
    float bv = bls[2048 + (wid << 6) + (nb << 4) + l15];
#pragma unroll
    for (int rb = 0; rb < 4; ++rb) acco[nb][rb] = (f32x4){bv, bv, bv, bv};
  }
#pragma unroll 1
  for (int e = 0; e < 8; ++e) {
    if (e < 7) {
      const unsigned short* nsrc = wall + (size_t)(53 + e) * 16384;
      unsigned short* ndst = wbls[(e + 1) & 1];
#pragma unroll
      for (int r = 0; r < 4; ++r) {
        int seg = r * 8 + wid;
        gload_lds16(nsrc + seg * 512 + lane * 8, ndst + seg * 512);
      }
      asm volatile("s_waitcnt vmcnt(4)" ::: "memory");
    } else {
      asm volatile("s_waitcnt vmcnt(0)" ::: "memory");
    }
    SCHED0();
    __builtin_amdgcn_s_barrier();
    SCHED0();
    bf16x8 ae[4];
#pragma unroll
    for (int rb = 0; rb < 4; ++rb)
      ae[rb] = *(const bf16x8*)(h2s + (size_t)(((e << 2) + rb) << 6) * 8 + (size_t)lane * 8);
    const unsigned short* wc = wbls[e & 1];
#pragma unroll
    for (int nb = 0; nb < 4; ++nb) {
      bf16x8 bb = *(const bf16x8*)(wc + (size_t)((((wid << 2) + nb) << 6) + lane) * 8);
#pragma unroll
      for (int rb = 0; rb < 4; ++rb)
        acco[nb][rb] = __builtin_amdgcn_mfma_f32_16x16x32_bf16(ae[rb], bb, acco[nb][rb], 0, 0, 0);
    }
    if (e < 7) {
      asm volatile("s_waitcnt lgkmcnt(0)" ::: "memory");
      SCHED0();
      __builtin_amdgcn_s_barrier();
      SCHED0();
    }
  }
#pragma unroll
  for (int nb = 0; nb < 4; ++nb) {
    int n = (wid << 6) + (nb << 4) + l15;
    if (n < NLAB) {
#pragma unroll
      for (int rb = 0; rb < 4; ++rb)
#pragma unroll
        for (int reg = 0; reg < 4; ++reg) {
          int r = (rb << 4) + ((lane >> 4) << 2) + reg;
          out[(size_t)(b0 + r) * NLAB + n] = acco[nb][rb][reg];
        }
    }
  }
}

extern "C" void kernel_launch(void* const* d_in, const int* in_sizes, int n_in,
                              void* d_out, int out_size, void* d_ws, size_t ws_size,
                              hipStream_t stream) {
  const int* car_idx    = (const int*)d_in[0];
  const int* region_idx = (const int*)d_in[1];
  const int* poi_idx    = (const int*)d_in[2];
  const int* week_idx   = (const int*)d_in[3];
  const int* time_idx   = (const int*)d_in[4];
  const float* car_emb    = (const float*)d_in[5];
  const float* region_emb = (const float*)d_in[6];
  const float* poi_emb    = (const float*)d_in[7];
  const float* week_emb   = (const float*)d_in[8];
  const float* time_emb   = (const float*)d_in[9];
  const float* Wih0 = (const float*)d_in[10];
  const float* Whh0 = (const float*)d_in[11];
  const float* bih0 = (const float*)d_in[12];
  const float* bhh0 = (const float*)d_in[13];
  const float* Wih1 = (const float*)d_in[14];
  const float* Whh1 = (const float*)d_in[15];
  const float* bih1 = (const float*)d_in[16];
  const float* bhh1 = (const float*)d_in[17];
  const float* Wout = (const float*)d_in[18];
  const float* bout = (const float*)d_in[19];

  // workspace: xfrag (20 MB), weight chunk wall (60 x 32 KB), bias blob (16 KB)
  unsigned short* xfrag = (unsigned short*)d_ws;       // 10,485,760 bf16
  unsigned short* wallp = xfrag + 10485760;            // 983,040 bf16
  float* bblob = (float*)(wallp + 983040);             // 4096 f32

  prep_w<<<3856, 256, 0, stream>>>(Wih0, Whh0, bih0, bhh0, Wih1, Whh1, bih1, bhh1,
                                   Wout, bout, wallp, bblob);
  gather_x<<<640, 256, 0, stream>>>(car_idx, region_idx, poi_idx, week_idx, time_idx,
                                    car_emb, region_emb, poi_emb, week_emb, time_emb, xfrag);
  lstm_fused<<<256, 512, 0, stream>>>(xfrag, wallp, bblob, (float*)d_out);
}